// Round 29
// baseline (309.685 us; speedup 1.0000x reference)
//
#include <hip/hip_runtime.h>
#include <hip/hip_bf16.h>

#define DEV __device__ __forceinline__

typedef short s16x8 __attribute__((ext_vector_type(8)));
typedef float f32x4 __attribute__((ext_vector_type(4)));

DEV float bflo(unsigned int w) { return __uint_as_float(w << 16); }
DEV float bfhi(unsigned int w) { return __uint_as_float(w & 0xFFFF0000u); }
DEV unsigned short f2bf(float f) {
    unsigned int u = __float_as_uint(f);
    u += 0x7FFFu + ((u >> 16) & 1u);
    return (unsigned short)(u >> 16);
}
DEV unsigned int pack2(float a, float b) {
    return (unsigned int)f2bf(a) | ((unsigned int)f2bf(b) << 16);
}
DEV void unp8(uint4 u, float* o) {
    o[0] = bflo(u.x); o[1] = bfhi(u.x); o[2] = bflo(u.y); o[3] = bfhi(u.y);
    o[4] = bflo(u.z); o[5] = bfhi(u.z); o[6] = bflo(u.w); o[7] = bfhi(u.w);
}

// ---------------- prep: build transposed weight views (all f32) ----------------
__global__ void prep_kernel(
    const float* __restrict__ Wq, const float* __restrict__ bq,
    const float* __restrict__ Wk, const float* __restrict__ bk,
    const float* __restrict__ Wv, const float* __restrict__ bv,
    const float* __restrict__ We, const float* __restrict__ Wsk,
    const float* __restrict__ bsk, const float* __restrict__ W1,
    float* __restrict__ WallT, float* __restrict__ biasAll,
    float* __restrict__ WeT, float* __restrict__ W1T)
{
    int t = blockIdx.x * 256 + threadIdx.x;
    if (t < 384 * 64) {
        int c = t >> 6, j = t & 63;
        float val;
        if (c < 64)       val = Wq[j * 64 + c];
        else if (c < 128) val = Wk[j * 64 + (c - 64)];
        else if (c < 192) val = Wv[j * 64 + (c - 128)];
        else if (c < 256) val = Wsk[j * 64 + (c - 192)];
        else {
            int hj = c - 256, h = hj >> 5, jj = hj & 31;
            float a = 0.f;
            for (int d = 0; d < 16; ++d)
                a += Wq[j * 64 + h * 16 + d] * We[jj * 64 + h * 16 + d];
            val = a;
        }
        WallT[c * 64 + j] = val;
        return;
    }
    t -= 384 * 64;
    if (t < 384) {
        float val;
        if (t < 64)       val = bq[t];
        else if (t < 128) val = bk[t - 64];
        else if (t < 192) val = bv[t - 128];
        else if (t < 256) val = bsk[t - 192];
        else {
            int hj = t - 256, h = hj >> 5, jj = hj & 31;
            float a = 0.f;
            for (int d = 0; d < 16; ++d)
                a += bq[h * 16 + d] * We[jj * 64 + h * 16 + d];
            val = a;
        }
        biasAll[t] = val;
        return;
    }
    t -= 384;
    if (t < 64 * 32) { int c = t >> 5, j = t & 31; WeT[t] = We[j * 64 + c]; return; }
    t -= 64 * 32;
    if (t < 128 * 64) { int c = t >> 6, j = t & 63; W1T[t] = W1[j * 128 + c]; return; }
}

// prep2: pack WallT into MFMA B-fragment order, bf16.
__global__ __launch_bounds__(256) void prep2_kernel(const float* __restrict__ WallT,
                                                    unsigned short* __restrict__ Wfrag)
{
    int t = blockIdx.x * 256 + threadIdx.x;
    if (t >= 24576) return;
    int j = t & 7, l = (t >> 3) & 63, kh = (t >> 9) & 1, nt = t >> 10;
    int col = nt * 16 + (l & 15);
    int kidx = kh * 32 + (l >> 4) * 8 + j;
    Wfrag[t] = f2bf(WallT[col * 64 + kidx]);
}

// prep3: pack W1 [64][128] and W2 [128][64] into B-fragment order, bf16.
__global__ __launch_bounds__(256) void prep3_kernel(const float* __restrict__ W1,
                                                    const float* __restrict__ W2,
                                                    unsigned short* __restrict__ W1frag,
                                                    unsigned short* __restrict__ W2frag)
{
    int t = blockIdx.x * 256 + threadIdx.x;
    if (t < 8192) {
        int j = t & 7, l = (t >> 3) & 63, kh = (t >> 9) & 1, nt = t >> 10;
        int col = nt * 16 + (l & 15);
        int kidx = kh * 32 + (l >> 4) * 8 + j;
        W1frag[t] = f2bf(W1[kidx * 128 + col]);
        return;
    }
    t -= 8192;
    if (t < 8192) {
        int j = t & 7, l = (t >> 3) & 63, kh = (t >> 9) & 3, nt = t >> 11;
        int col = nt * 16 + (l & 15);
        int kidx = kh * 32 + (l >> 4) * 8 + j;
        W2frag[t] = f2bf(W2[kidx * 64 + col]);
    }
}

// ---------------- gemm (fused with LN1): [64 nodes] x [K=64] @ [64 x 384] ----------
// r29 change: skip range now emits xs = x + skip (pre-summed) — shifts 25.6MB of
// reads from latency-bound agg to this BW-idle kernel (x re-read is coalesced:
// per (nt,r) lanes 0..15 cover 64 contiguous bytes).
__global__ __launch_bounds__(256, 2) void gemm_kernel(
    const float* __restrict__ x, const float* __restrict__ ln1w,
    const float* __restrict__ ln1b, const unsigned short* __restrict__ Wfrag,
    const float* __restrict__ biasAll,
    unsigned short* __restrict__ q, unsigned short* __restrict__ k,
    unsigned short* __restrict__ v, unsigned short* __restrict__ qp,
    float* __restrict__ xs, int nN)
{
    __shared__ unsigned short lw[24576];
    __shared__ unsigned short ly[4096];
    int tid = threadIdx.x;
    int m0 = blockIdx.x * 64;

    {   // W: 3072 uint4
        const uint4* wg = (const uint4*)Wfrag;
        uint4* wl = (uint4*)lw;
        #pragma unroll
        for (int i = 0; i < 12; ++i) wl[tid + i * 256] = wg[tid + i * 256];
    }
    {   // fused LN1 + swizzled Y staging
        int r = tid >> 2, p = tid & 3;
        int n = m0 + r;
        unsigned int pk[8] = {0, 0, 0, 0, 0, 0, 0, 0};
        if (n < nN) {
            const float4* xr = (const float4*)(x + (size_t)n * 64 + p * 16);
            float yv[16];
            float s = 0.f, sq = 0.f;
            #pragma unroll
            for (int i = 0; i < 4; ++i) {
                float4 u = xr[i];
                yv[i * 4 + 0] = u.x; yv[i * 4 + 1] = u.y;
                yv[i * 4 + 2] = u.z; yv[i * 4 + 3] = u.w;
                s += u.x + u.y + u.z + u.w;
                sq += u.x * u.x + u.y * u.y + u.z * u.z + u.w * u.w;
            }
            s  += __shfl_xor(s, 1);  s  += __shfl_xor(s, 2);
            sq += __shfl_xor(sq, 1); sq += __shfl_xor(sq, 2);
            float m = s * (1.f / 64.f);
            float var = sq * (1.f / 64.f) - m * m;
            float rstd = rsqrtf(var + 1e-5f);
            const float4* wr = (const float4*)(ln1w + p * 16);
            const float4* br = (const float4*)(ln1b + p * 16);
            #pragma unroll
            for (int i = 0; i < 4; ++i) {
                float4 w = wr[i], b = br[i];
                float a0 = (yv[i * 4 + 0] - m) * rstd * w.x + b.x;
                float a1 = (yv[i * 4 + 1] - m) * rstd * w.y + b.y;
                float a2 = (yv[i * 4 + 2] - m) * rstd * w.z + b.z;
                float a3 = (yv[i * 4 + 3] - m) * rstd * w.w + b.w;
                pk[i * 2 + 0] = pack2(a0, a1);
                pk[i * 2 + 1] = pack2(a2, a3);
            }
        }
        uint4* lyv = (uint4*)ly;
        lyv[r * 8 + ((2 * p + 0) ^ (r & 7))] = make_uint4(pk[0], pk[1], pk[2], pk[3]);
        lyv[r * 8 + ((2 * p + 1) ^ (r & 7))] = make_uint4(pk[4], pk[5], pk[6], pk[7]);
    }
    __syncthreads();

    int w = tid >> 6, l = tid & 63;
    int hi = l >> 4, colb = l & 15;
    int lr = w * 16 + colb;
    s16x8 a0 = *(const s16x8*)&ly[(lr * 8 + ((0 + hi) ^ (lr & 7))) * 8];
    s16x8 a1 = *(const s16x8*)&ly[(lr * 8 + ((4 + hi) ^ (lr & 7))) * 8];

    f32x4 acc[24];
    #pragma unroll
    for (int nt = 0; nt < 24; ++nt) {
        float b0 = biasAll[nt * 16 + colb];
        acc[nt] = (f32x4){b0, b0, b0, b0};
    }
    #pragma unroll
    for (int nt = 0; nt < 24; ++nt) {
        s16x8 b0 = *(const s16x8*)&lw[((nt * 2 + 0) * 64 + l) * 8];
        s16x8 b1 = *(const s16x8*)&lw[((nt * 2 + 1) * 64 + l) * 8];
        acc[nt] = __builtin_amdgcn_mfma_f32_16x16x32_bf16(a0, b0, acc[nt], 0, 0, 0);
        acc[nt] = __builtin_amdgcn_mfma_f32_16x16x32_bf16(a1, b1, acc[nt], 0, 0, 0);
    }

    int rbase = m0 + w * 16 + hi * 4;
    #pragma unroll
    for (int nt = 0; nt < 24; ++nt) {
        int c = nt * 16 + colb;
        #pragma unroll
        for (int r = 0; r < 4; ++r) {
            int node = rbase + r;
            if (node >= nN) continue;
            float val = acc[nt][r];
            if (nt < 4)       q[(size_t)node * 64 + c] = f2bf(val);
            else if (nt < 8)  k[(size_t)node * 64 + (c - 64)] = f2bf(val);
            else if (nt < 12) v[(size_t)node * 64 + (c - 128)] = f2bf(val);
            else if (nt < 16) xs[(size_t)node * 64 + (c - 192)] =
                                  x[(size_t)node * 64 + (c - 192)] + val;
            else              qp[(size_t)node * 128 + (c - 256)] = f2bf(val);
        }
    }
}

// ---------------- CSR build ----------------
__global__ __launch_bounds__(256) void deg_kernel(const int* __restrict__ ei,
                                                  int* __restrict__ deg,
                                                  int* __restrict__ rank, int nE)
{
    int e = blockIdx.x * 256 + threadIdx.x;
    if (e >= nE) return;
    rank[e] = atomicAdd(&deg[ei[nE + e]], 1);
}

// multi-block scan, 3 phases. Block = 2048 elements.
__global__ __launch_bounds__(256) void scanA_kernel(const int* __restrict__ deg,
                                                    int* __restrict__ bsum, int nN)
{
    __shared__ int sd[256];
    int b = blockIdx.x, t = threadIdx.x;
    int i0 = b * 2048 + t * 8;
    int s = 0;
    #pragma unroll
    for (int u = 0; u < 8; ++u) { int id = i0 + u; s += (id < nN) ? deg[id] : 0; }
    sd[t] = s;
    __syncthreads();
    for (int d = 128; d > 0; d >>= 1) {
        if (t < d) sd[t] += sd[t + d];
        __syncthreads();
    }
    if (t == 0) bsum[b] = sd[0];
}

__global__ __launch_bounds__(1024) void scanB_kernel(int* __restrict__ bsum, int nb)
{
    __shared__ int sd[1024];
    int t = threadIdx.x;
    int v = (t < nb) ? bsum[t] : 0;
    sd[t] = v;
    __syncthreads();
    for (int d = 1; d < 1024; d <<= 1) {
        int tmp = (t >= d) ? sd[t - d] : 0;
        __syncthreads();
        sd[t] += tmp;
        __syncthreads();
    }
    if (t < nb) bsum[t] = sd[t] - v;   // exclusive
}

__global__ __launch_bounds__(256) void scanC_kernel(const int* __restrict__ deg,
                                                    const int* __restrict__ bsum,
                                                    int* __restrict__ start,
                                                    int nN, int nE)
{
    __shared__ int sd[256];
    int b = blockIdx.x, t = threadIdx.x;
    int i0 = b * 2048 + t * 8;
    int lv[8];
    int s = 0;
    #pragma unroll
    for (int u = 0; u < 8; ++u) {
        int id = i0 + u;
        lv[u] = (id < nN) ? deg[id] : 0;
        s += lv[u];
    }
    sd[t] = s;
    __syncthreads();
    for (int d = 1; d < 256; d <<= 1) {
        int tmp = (t >= d) ? sd[t - d] : 0;
        __syncthreads();
        sd[t] += tmp;
        __syncthreads();
    }
    int run = bsum[b] + sd[t] - s;
    #pragma unroll
    for (int u = 0; u < 8; ++u) {
        int id = i0 + u;
        if (id < nN) start[id] = run;
        run += lv[u];
    }
    if (b == 0 && t == 0) start[nN] = nE;
}

// scatter: indices ONLY; no atomics (rank captured in deg).
__global__ __launch_bounds__(256) void scatter_kernel(
    const int* __restrict__ ei, const int* __restrict__ start,
    const int* __restrict__ rank, int2* __restrict__ spair, int nE)
{
    int e = blockIdx.x * 256 + threadIdx.x;
    if (e >= nE) return;
    int dst = ei[nE + e];
    int pos = start[dst] + rank[e];
    spair[pos] = make_int2(ei[e], e);
}

// ---------------- agg (fused with pre_final): 8 threads/node (head x half) --------
// attr gathered DIRECTLY from f32 ea (128B aligned rows — no over-fetch);
// spair batched via coalesced int2 preload + shfl broadcast.
// r29: epilogue reads pre-summed xs (= x + skip) — 25.6MB less traffic here.
__global__ __launch_bounds__(256) void agg_kernel(
    const int* __restrict__ start, const int2* __restrict__ spair,
    const float* __restrict__ ea,
    const unsigned short* __restrict__ q, const unsigned short* __restrict__ k,
    const unsigned short* __restrict__ v, const unsigned short* __restrict__ qp,
    const float* __restrict__ WeT,
    const float* __restrict__ xs,
    const float* __restrict__ ln2w, const float* __restrict__ ln2b,
    float* __restrict__ xnf, unsigned short* __restrict__ hbf, int nN)
{
    int t = blockIdx.x * 256 + threadIdx.x;
    int n = t >> 3, sub = t & 7, h = sub >> 1, half = sub & 1;
    if (n >= nN) return;
    int l = threadIdx.x & 63;
    int gbase = l & ~7;

    float qv[8];
    { uint4 r = *(const uint4*)(q + (size_t)n * 64 + h * 16 + half * 8); unp8(r, qv); }
    float pj[16];
    {
        const uint4* r = (const uint4*)(qp + (size_t)n * 128 + h * 32 + half * 16);
        unp8(r[0], pj); unp8(r[1], pj + 8);
    }
    float acc[8], s[16];
    #pragma unroll
    for (int c = 0; c < 8; ++c) acc[c] = 0.f;
    #pragma unroll
    for (int j = 0; j < 16; ++j) s[j] = 0.f;
    float dn = 0.f;

    int i0 = start[n], i1 = start[n + 1];
    #pragma unroll 1
    for (int base = i0; base < i1; base += 8) {
        int myi = base + sub;
        int2 se = (myi < i1) ? spair[myi] : make_int2(0, 0);
        int lim = min(8, i1 - base);
        #pragma unroll 2
        for (int j = 0; j < lim; ++j) {
            int src = __shfl(se.x, gbase + j);
            int e   = __shfl(se.y, gbase + j);
            float attr[16];
            {
                const float4* ar = (const float4*)(ea + (size_t)e * 32 + half * 16);
                #pragma unroll
                for (int ii = 0; ii < 4; ++ii) {
                    float4 u = ar[ii];
                    attr[ii * 4 + 0] = u.x; attr[ii * 4 + 1] = u.y;
                    attr[ii * 4 + 2] = u.z; attr[ii * 4 + 3] = u.w;
                }
            }
            float part = 0.f;
            {
                uint4 r = *(const uint4*)(k + (size_t)src * 64 + h * 16 + half * 8);
                float kt[8];
                unp8(r, kt);
                #pragma unroll
                for (int d = 0; d < 8; ++d) part += qv[d] * kt[d];
            }
            #pragma unroll
            for (int j2 = 0; j2 < 16; ++j2) part += attr[j2] * pj[j2];
            float al = part + __shfl_xor(part, 1);
            float ex = __expf(al * 0.25f);
            dn += ex;
            {
                uint4 r = *(const uint4*)(v + (size_t)src * 64 + h * 16 + half * 8);
                float vt[8];
                unp8(r, vt);
                #pragma unroll
                for (int c = 0; c < 8; ++c) acc[c] += ex * vt[c];
            }
            #pragma unroll
            for (int j2 = 0; j2 < 16; ++j2) s[j2] += ex * attr[j2];
        }
    }

    // factored edge projection, split across the lane pair:
    int ch_own = h * 16 + half * 8;
    int ch_oth = h * 16 + (1 - half) * 8;
    float proj_oth[8];
    float po[8];
    #pragma unroll
    for (int c = 0; c < 8; ++c) {
        const float* wo = WeT + (size_t)(ch_own + c) * 32 + half * 16;
        const float* wx = WeT + (size_t)(ch_oth + c) * 32 + half * 16;
        float a = 0.f, b = 0.f;
        #pragma unroll
        for (int j = 0; j < 16; ++j) { a += wo[j] * s[j]; b += wx[j] * s[j]; }
        po[c] = a; proj_oth[c] = b;
    }
    #pragma unroll
    for (int c = 0; c < 8; ++c) acc[c] += po[c] + __shfl_xor(proj_oth[c], 1);

    // ---- fused pre_final epilogue ----
    float inv = dn != 0.f ? 1.f / dn : 0.f;
    float xn[8];
    {
        const float4* sr = (const float4*)(xs + (size_t)n * 64 + ch_own);
        float4 s0 = sr[0], s1 = sr[1];
        xn[0] = s0.x + acc[0] * inv;
        xn[1] = s0.y + acc[1] * inv;
        xn[2] = s0.z + acc[2] * inv;
        xn[3] = s0.w + acc[3] * inv;
        xn[4] = s1.x + acc[4] * inv;
        xn[5] = s1.y + acc[5] * inv;
        xn[6] = s1.z + acc[6] * inv;
        xn[7] = s1.w + acc[7] * inv;
    }
    float sm = 0.f, sq = 0.f;
    #pragma unroll
    for (int c = 0; c < 8; ++c) { sm += xn[c]; sq += xn[c] * xn[c]; }
    sm += __shfl_xor(sm, 1); sm += __shfl_xor(sm, 2); sm += __shfl_xor(sm, 4);
    sq += __shfl_xor(sq, 1); sq += __shfl_xor(sq, 2); sq += __shfl_xor(sq, 4);
    float m = sm * (1.f / 64.f);
    float var = sq * (1.f / 64.f) - m * m;
    float rstd = rsqrtf(var + 1e-5f);

    float4* xw = (float4*)(xnf + (size_t)n * 64 + ch_own);
    xw[0] = make_float4(xn[0], xn[1], xn[2], xn[3]);
    xw[1] = make_float4(xn[4], xn[5], xn[6], xn[7]);

    const float4* wr = (const float4*)(ln2w + ch_own);
    const float4* br = (const float4*)(ln2b + ch_own);
    float4 w0 = wr[0], w1 = wr[1], b0 = br[0], b1 = br[1];
    float h0 = (xn[0] - m) * rstd * w0.x + b0.x;
    float h1 = (xn[1] - m) * rstd * w0.y + b0.y;
    float h2 = (xn[2] - m) * rstd * w0.z + b0.z;
    float h3 = (xn[3] - m) * rstd * w0.w + b0.w;
    float h4 = (xn[4] - m) * rstd * w1.x + b1.x;
    float h5 = (xn[5] - m) * rstd * w1.y + b1.y;
    float h6 = (xn[6] - m) * rstd * w1.z + b1.z;
    float h7 = (xn[7] - m) * rstd * w1.w + b1.w;
    uint2* hw = (uint2*)(hbf + (size_t)n * 64 + ch_own);
    hw[0] = make_uint2(pack2(h0, h1), pack2(h2, h3));
    hw[1] = make_uint2(pack2(h4, h5), pack2(h6, h7));
}

// ---------------- mlp: h @ W1 -> GELU -> @ W2 + xn + b2, all MFMA ----------------
__global__ __launch_bounds__(256, 2) void mlp_kernel(
    const unsigned short* __restrict__ hbf, const float* __restrict__ xnf,
    const unsigned short* __restrict__ W1frag, const unsigned short* __restrict__ W2frag,
    const float* __restrict__ b1, const float* __restrict__ b2,
    float* __restrict__ out, int nN)
{
    __shared__ unsigned short lw1[8192];
    __shared__ unsigned short lw2[8192];
    __shared__ unsigned short lh[4096];
    __shared__ unsigned short lg[8192];
    int tid = threadIdx.x;
    int m0 = blockIdx.x * 64;

    {
        const uint4* g1 = (const uint4*)W1frag;
        uint4* l1 = (uint4*)lw1;
        #pragma unroll
        for (int i = 0; i < 4; ++i) l1[tid + i * 256] = g1[tid + i * 256];
        const uint4* g2 = (const uint4*)W2frag;
        uint4* l2 = (uint4*)lw2;
        #pragma unroll
        for (int i = 0; i < 4; ++i) l2[tid + i * 256] = g2[tid + i * 256];
    }
    {
        int r = tid >> 2, p = tid & 3;
        int n = m0 + r;
        uint4 a = make_uint4(0, 0, 0, 0), b = a;
        if (n < nN) {
            const uint4* hr = (const uint4*)(hbf + (size_t)n * 64);
            a = hr[p]; b = hr[p + 4];
        }
        uint4* lhv = (uint4*)lh;
        lhv[r * 8 + (p ^ (r & 7))] = a;
        lhv[r * 8 + ((p + 4) ^ (r & 7))] = b;
    }
    __syncthreads();

    int w = tid >> 6, l = tid & 63;
    int hi = l >> 4, colb = l & 15;
    int lr = w * 16 + colb;
    s16x8 a0 = *(const s16x8*)&lh[(lr * 8 + ((0 + hi) ^ (lr & 7))) * 8];
    s16x8 a1 = *(const s16x8*)&lh[(lr * 8 + ((4 + hi) ^ (lr & 7))) * 8];

    f32x4 acc1[8];
    #pragma unroll
    for (int nt = 0; nt < 8; ++nt) {
        float bb = b1[nt * 16 + colb];
        acc1[nt] = (f32x4){bb, bb, bb, bb};
    }
    #pragma unroll
    for (int nt = 0; nt < 8; ++nt) {
        s16x8 b0 = *(const s16x8*)&lw1[((nt * 2 + 0) * 64 + l) * 8];
        s16x8 b1v = *(const s16x8*)&lw1[((nt * 2 + 1) * 64 + l) * 8];
        acc1[nt] = __builtin_amdgcn_mfma_f32_16x16x32_bf16(a0, b0, acc1[nt], 0, 0, 0);
        acc1[nt] = __builtin_amdgcn_mfma_f32_16x16x32_bf16(a1, b1v, acc1[nt], 0, 0, 0);
    }

    int rb = w * 16 + hi * 4;
    #pragma unroll
    for (int nt = 0; nt < 8; ++nt) {
        int c = nt * 16 + colb;
        int chunk = c >> 3;
        #pragma unroll
        for (int r = 0; r < 4; ++r) {
            float a = acc1[nt][r];
            float gl = 0.5f * a * (1.f + erff(a * 0.70710678118f));
            int node = rb + r;
            lg[node * 128 + (chunk ^ (node & 15)) * 8 + (c & 7)] = f2bf(gl);
        }
    }
    __syncthreads();

    s16x8 ag[4];
    #pragma unroll
    for (int kh = 0; kh < 4; ++kh) {
        int chunk = kh * 4 + hi;
        ag[kh] = *(const s16x8*)&lg[lr * 128 + ((chunk ^ (lr & 15)) * 8)];
    }
    f32x4 acc2[4];
    #pragma unroll
    for (int nt = 0; nt < 4; ++nt) acc2[nt] = (f32x4){0.f, 0.f, 0.f, 0.f};
    #pragma unroll
    for (int nt = 0; nt < 4; ++nt) {
        #pragma unroll
        for (int kh = 0; kh < 4; ++kh) {
            s16x8 bb = *(const s16x8*)&lw2[((nt * 4 + kh) * 64 + l) * 8];
            acc2[nt] = __builtin_amdgcn_mfma_f32_16x16x32_bf16(ag[kh], bb, acc2[nt], 0, 0, 0);
        }
    }

    #pragma unroll
    for (int nt = 0; nt < 4; ++nt) {
        int c = nt * 16 + colb;
        float b2v = b2[c];
        #pragma unroll
        for (int r = 0; r < 4; ++r) {
            int node = m0 + rb + r;
            if (node >= nN) continue;
            out[(size_t)node * 64 + c] = acc2[nt][r] + xnf[(size_t)node * 64 + c] + b2v;
        }
    }
}

extern "C" void kernel_launch(void* const* d_in, const int* in_sizes, int n_in,
                              void* d_out, int out_size, void* d_ws, size_t ws_size,
                              hipStream_t stream)
{
    const float* x    = (const float*)d_in[0];
    const int*   ei   = (const int*)d_in[1];
    const float* ea   = (const float*)d_in[2];
    const float* ln1w = (const float*)d_in[3];
    const float* ln1b = (const float*)d_in[4];
    const float* ln2w = (const float*)d_in[5];
    const float* ln2b = (const float*)d_in[6];
    const float* Wq   = (const float*)d_in[7];
    const float* bq   = (const float*)d_in[8];
    const float* Wk   = (const float*)d_in[9];
    const float* bk   = (const float*)d_in[10];
    const float* Wv   = (const float*)d_in[11];
    const float* bv   = (const float*)d_in[12];
    const float* We   = (const float*)d_in[13];
    const float* Wsk  = (const float*)d_in[14];
    const float* bsk  = (const float*)d_in[15];
    const float* W1   = (const float*)d_in[16];
    const float* b1   = (const float*)d_in[17];
    const float* W2   = (const float*)d_in[18];
    const float* b2   = (const float*)d_in[19];

    int nN = in_sizes[0] / 64;
    int nE = in_sizes[1] / 2;
    int nb = (nN + 2047) / 2048;

    char* wsb = (char*)d_ws;
    size_t off = 0;
    auto take = [&](size_t bytes) {
        char* p = wsb + off;
        off += (bytes + 255) & ~(size_t)255;
        return p;
    };
    unsigned short* q  = (unsigned short*)take((size_t)nN * 64 * 2);
    unsigned short* kk = (unsigned short*)take((size_t)nN * 64 * 2);
    unsigned short* vv = (unsigned short*)take((size_t)nN * 64 * 2);
    unsigned short* qp = (unsigned short*)take((size_t)nN * 128 * 2);
    float* xs      = (float*)take((size_t)nN * 64 * 4);
    float* WallT   = (float*)take(384 * 64 * 4);
    float* biasAll = (float*)take(384 * 4);
    float* WeT     = (float*)take(64 * 32 * 4);
    float* W1T     = (float*)take(128 * 64 * 4);
    unsigned short* Wfrag  = (unsigned short*)take(24576 * 2);
    unsigned short* W1frag = (unsigned short*)take(8192 * 2);
    unsigned short* W2frag = (unsigned short*)take(8192 * 2);
    float* xnf = (float*)take((size_t)nN * 64 * 4);
    unsigned short* hbf = (unsigned short*)take((size_t)nN * 64 * 2);
    int* deg    = (int*)take((size_t)nN * 4);
    int* startp = (int*)take((size_t)(nN + 1) * 4);
    int* bsum   = (int*)take((size_t)(nb + 1) * 4);
    int* rank   = (int*)take((size_t)nE * 4);
    int2* spair = (int2*)take((size_t)nE * 8);

    (void)hipMemsetAsync(deg, 0, (size_t)nN * 4, stream);
    prep_kernel<<<138, 256, 0, stream>>>(Wq, bq, Wk, bk, Wv, bv, We, Wsk, bsk, W1,
                                         WallT, biasAll, WeT, W1T);
    prep2_kernel<<<96, 256, 0, stream>>>(WallT, Wfrag);
    prep3_kernel<<<64, 256, 0, stream>>>(W1, W2, W1frag, W2frag);
    gemm_kernel<<<(nN + 63) / 64, 256, 0, stream>>>(x, ln1w, ln1b, Wfrag, biasAll,
                                                    q, kk, vv, qp, xs, nN);
    deg_kernel<<<(nE + 255) / 256, 256, 0, stream>>>(ei, deg, rank, nE);
    scanA_kernel<<<nb, 256, 0, stream>>>(deg, bsum, nN);
    scanB_kernel<<<1, 1024, 0, stream>>>(bsum, nb);
    scanC_kernel<<<nb, 256, 0, stream>>>(deg, bsum, startp, nN, nE);
    scatter_kernel<<<(nE + 255) / 256, 256, 0, stream>>>(ei, startp, rank, spair, nE);
    agg_kernel<<<((size_t)nN * 8 + 255) / 256, 256, 0, stream>>>(
        startp, spair, ea, q, kk, vv, qp, WeT, xs, ln2w, ln2b,
        xnf, hbf, nN);
    mlp_kernel<<<(nN + 63) / 64, 256, 0, stream>>>(hbf, xnf, W1frag, W2frag,
                                                   b1, b2, (float*)d_out, nN);
}

// Round 30
// 304.290 us; speedup vs baseline: 1.0177x; 1.0177x over previous
//
#include <hip/hip_runtime.h>
#include <hip/hip_bf16.h>

#define DEV __device__ __forceinline__

typedef short s16x8 __attribute__((ext_vector_type(8)));
typedef float f32x4 __attribute__((ext_vector_type(4)));

DEV float bflo(unsigned int w) { return __uint_as_float(w << 16); }
DEV float bfhi(unsigned int w) { return __uint_as_float(w & 0xFFFF0000u); }
DEV unsigned short f2bf(float f) {
    unsigned int u = __float_as_uint(f);
    u += 0x7FFFu + ((u >> 16) & 1u);
    return (unsigned short)(u >> 16);
}
DEV unsigned int pack2(float a, float b) {
    return (unsigned int)f2bf(a) | ((unsigned int)f2bf(b) << 16);
}
DEV void unp8(uint4 u, float* o) {
    o[0] = bflo(u.x); o[1] = bfhi(u.x); o[2] = bflo(u.y); o[3] = bfhi(u.y);
    o[4] = bflo(u.z); o[5] = bfhi(u.z); o[6] = bflo(u.w); o[7] = bfhi(u.w);
}

// ---------------- prep: build transposed weight views (all f32) ----------------
__global__ void prep_kernel(
    const float* __restrict__ Wq, const float* __restrict__ bq,
    const float* __restrict__ Wk, const float* __restrict__ bk,
    const float* __restrict__ Wv, const float* __restrict__ bv,
    const float* __restrict__ We, const float* __restrict__ Wsk,
    const float* __restrict__ bsk, const float* __restrict__ W1,
    float* __restrict__ WallT, float* __restrict__ biasAll,
    float* __restrict__ WeT, float* __restrict__ W1T)
{
    int t = blockIdx.x * 256 + threadIdx.x;
    if (t < 384 * 64) {
        int c = t >> 6, j = t & 63;
        float val;
        if (c < 64)       val = Wq[j * 64 + c];
        else if (c < 128) val = Wk[j * 64 + (c - 64)];
        else if (c < 192) val = Wv[j * 64 + (c - 128)];
        else if (c < 256) val = Wsk[j * 64 + (c - 192)];
        else {
            int hj = c - 256, h = hj >> 5, jj = hj & 31;
            float a = 0.f;
            for (int d = 0; d < 16; ++d)
                a += Wq[j * 64 + h * 16 + d] * We[jj * 64 + h * 16 + d];
            val = a;
        }
        WallT[c * 64 + j] = val;
        return;
    }
    t -= 384 * 64;
    if (t < 384) {
        float val;
        if (t < 64)       val = bq[t];
        else if (t < 128) val = bk[t - 64];
        else if (t < 192) val = bv[t - 128];
        else if (t < 256) val = bsk[t - 192];
        else {
            int hj = t - 256, h = hj >> 5, jj = hj & 31;
            float a = 0.f;
            for (int d = 0; d < 16; ++d)
                a += bq[h * 16 + d] * We[jj * 64 + h * 16 + d];
            val = a;
        }
        biasAll[t] = val;
        return;
    }
    t -= 384;
    if (t < 64 * 32) { int c = t >> 5, j = t & 31; WeT[t] = We[j * 64 + c]; return; }
    t -= 64 * 32;
    if (t < 128 * 64) { int c = t >> 6, j = t & 63; W1T[t] = W1[j * 128 + c]; return; }
}

// prep2: pack WallT into MFMA B-fragment order, bf16.
__global__ __launch_bounds__(256) void prep2_kernel(const float* __restrict__ WallT,
                                                    unsigned short* __restrict__ Wfrag)
{
    int t = blockIdx.x * 256 + threadIdx.x;
    if (t >= 24576) return;
    int j = t & 7, l = (t >> 3) & 63, kh = (t >> 9) & 1, nt = t >> 10;
    int col = nt * 16 + (l & 15);
    int kidx = kh * 32 + (l >> 4) * 8 + j;
    Wfrag[t] = f2bf(WallT[col * 64 + kidx]);
}

// prep3: pack W1 [64][128] and W2 [128][64] into B-fragment order, bf16.
__global__ __launch_bounds__(256) void prep3_kernel(const float* __restrict__ W1,
                                                    const float* __restrict__ W2,
                                                    unsigned short* __restrict__ W1frag,
                                                    unsigned short* __restrict__ W2frag)
{
    int t = blockIdx.x * 256 + threadIdx.x;
    if (t < 8192) {
        int j = t & 7, l = (t >> 3) & 63, kh = (t >> 9) & 1, nt = t >> 10;
        int col = nt * 16 + (l & 15);
        int kidx = kh * 32 + (l >> 4) * 8 + j;
        W1frag[t] = f2bf(W1[kidx * 128 + col]);
        return;
    }
    t -= 8192;
    if (t < 8192) {
        int j = t & 7, l = (t >> 3) & 63, kh = (t >> 9) & 3, nt = t >> 11;
        int col = nt * 16 + (l & 15);
        int kidx = kh * 32 + (l >> 4) * 8 + j;
        W2frag[t] = f2bf(W2[kidx * 64 + col]);
    }
}

// ---------------- gemm (fused with LN1): [64 nodes] x [K=64] @ [64 x 384] ----------
__global__ __launch_bounds__(256, 2) void gemm_kernel(
    const float* __restrict__ x, const float* __restrict__ ln1w,
    const float* __restrict__ ln1b, const unsigned short* __restrict__ Wfrag,
    const float* __restrict__ biasAll,
    unsigned short* __restrict__ q, unsigned short* __restrict__ k,
    unsigned short* __restrict__ v, unsigned short* __restrict__ qp,
    float* __restrict__ skip, int nN)
{
    __shared__ unsigned short lw[24576];
    __shared__ unsigned short ly[4096];
    int tid = threadIdx.x;
    int m0 = blockIdx.x * 64;

    {   // W: 3072 uint4
        const uint4* wg = (const uint4*)Wfrag;
        uint4* wl = (uint4*)lw;
        #pragma unroll
        for (int i = 0; i < 12; ++i) wl[tid + i * 256] = wg[tid + i * 256];
    }
    {   // fused LN1 + swizzled Y staging
        int r = tid >> 2, p = tid & 3;
        int n = m0 + r;
        unsigned int pk[8] = {0, 0, 0, 0, 0, 0, 0, 0};
        if (n < nN) {
            const float4* xr = (const float4*)(x + (size_t)n * 64 + p * 16);
            float yv[16];
            float s = 0.f, sq = 0.f;
            #pragma unroll
            for (int i = 0; i < 4; ++i) {
                float4 u = xr[i];
                yv[i * 4 + 0] = u.x; yv[i * 4 + 1] = u.y;
                yv[i * 4 + 2] = u.z; yv[i * 4 + 3] = u.w;
                s += u.x + u.y + u.z + u.w;
                sq += u.x * u.x + u.y * u.y + u.z * u.z + u.w * u.w;
            }
            s  += __shfl_xor(s, 1);  s  += __shfl_xor(s, 2);
            sq += __shfl_xor(sq, 1); sq += __shfl_xor(sq, 2);
            float m = s * (1.f / 64.f);
            float var = sq * (1.f / 64.f) - m * m;
            float rstd = rsqrtf(var + 1e-5f);
            const float4* wr = (const float4*)(ln1w + p * 16);
            const float4* br = (const float4*)(ln1b + p * 16);
            #pragma unroll
            for (int i = 0; i < 4; ++i) {
                float4 w = wr[i], b = br[i];
                float a0 = (yv[i * 4 + 0] - m) * rstd * w.x + b.x;
                float a1 = (yv[i * 4 + 1] - m) * rstd * w.y + b.y;
                float a2 = (yv[i * 4 + 2] - m) * rstd * w.z + b.z;
                float a3 = (yv[i * 4 + 3] - m) * rstd * w.w + b.w;
                pk[i * 2 + 0] = pack2(a0, a1);
                pk[i * 2 + 1] = pack2(a2, a3);
            }
        }
        uint4* lyv = (uint4*)ly;
        lyv[r * 8 + ((2 * p + 0) ^ (r & 7))] = make_uint4(pk[0], pk[1], pk[2], pk[3]);
        lyv[r * 8 + ((2 * p + 1) ^ (r & 7))] = make_uint4(pk[4], pk[5], pk[6], pk[7]);
    }
    __syncthreads();

    int w = tid >> 6, l = tid & 63;
    int hi = l >> 4, colb = l & 15;
    int lr = w * 16 + colb;
    s16x8 a0 = *(const s16x8*)&ly[(lr * 8 + ((0 + hi) ^ (lr & 7))) * 8];
    s16x8 a1 = *(const s16x8*)&ly[(lr * 8 + ((4 + hi) ^ (lr & 7))) * 8];

    f32x4 acc[24];
    #pragma unroll
    for (int nt = 0; nt < 24; ++nt) {
        float b0 = biasAll[nt * 16 + colb];
        acc[nt] = (f32x4){b0, b0, b0, b0};
    }
    #pragma unroll
    for (int nt = 0; nt < 24; ++nt) {
        s16x8 b0 = *(const s16x8*)&lw[((nt * 2 + 0) * 64 + l) * 8];
        s16x8 b1 = *(const s16x8*)&lw[((nt * 2 + 1) * 64 + l) * 8];
        acc[nt] = __builtin_amdgcn_mfma_f32_16x16x32_bf16(a0, b0, acc[nt], 0, 0, 0);
        acc[nt] = __builtin_amdgcn_mfma_f32_16x16x32_bf16(a1, b1, acc[nt], 0, 0, 0);
    }

    int rbase = m0 + w * 16 + hi * 4;
    #pragma unroll
    for (int nt = 0; nt < 24; ++nt) {
        int c = nt * 16 + colb;
        #pragma unroll
        for (int r = 0; r < 4; ++r) {
            int node = rbase + r;
            if (node >= nN) continue;
            float val = acc[nt][r];
            if (nt < 4)       q[(size_t)node * 64 + c] = f2bf(val);
            else if (nt < 8)  k[(size_t)node * 64 + (c - 64)] = f2bf(val);
            else if (nt < 12) v[(size_t)node * 64 + (c - 128)] = f2bf(val);
            else if (nt < 16) skip[(size_t)node * 64 + (c - 192)] = val;
            else              qp[(size_t)node * 128 + (c - 256)] = f2bf(val);
        }
    }
}

// ---------------- CSR build ----------------
__global__ __launch_bounds__(256) void deg_kernel(const int* __restrict__ ei,
                                                  int* __restrict__ deg,
                                                  int* __restrict__ rank, int nE)
{
    int e = blockIdx.x * 256 + threadIdx.x;
    if (e >= nE) return;
    rank[e] = atomicAdd(&deg[ei[nE + e]], 1);
}

// multi-block scan, 3 phases. Block = 2048 elements.
__global__ __launch_bounds__(256) void scanA_kernel(const int* __restrict__ deg,
                                                    int* __restrict__ bsum, int nN)
{
    __shared__ int sd[256];
    int b = blockIdx.x, t = threadIdx.x;
    int i0 = b * 2048 + t * 8;
    int s = 0;
    #pragma unroll
    for (int u = 0; u < 8; ++u) { int id = i0 + u; s += (id < nN) ? deg[id] : 0; }
    sd[t] = s;
    __syncthreads();
    for (int d = 128; d > 0; d >>= 1) {
        if (t < d) sd[t] += sd[t + d];
        __syncthreads();
    }
    if (t == 0) bsum[b] = sd[0];
}

__global__ __launch_bounds__(1024) void scanB_kernel(int* __restrict__ bsum, int nb)
{
    __shared__ int sd[1024];
    int t = threadIdx.x;
    int v = (t < nb) ? bsum[t] : 0;
    sd[t] = v;
    __syncthreads();
    for (int d = 1; d < 1024; d <<= 1) {
        int tmp = (t >= d) ? sd[t - d] : 0;
        __syncthreads();
        sd[t] += tmp;
        __syncthreads();
    }
    if (t < nb) bsum[t] = sd[t] - v;   // exclusive
}

__global__ __launch_bounds__(256) void scanC_kernel(const int* __restrict__ deg,
                                                    const int* __restrict__ bsum,
                                                    int* __restrict__ start,
                                                    int nN, int nE)
{
    __shared__ int sd[256];
    int b = blockIdx.x, t = threadIdx.x;
    int i0 = b * 2048 + t * 8;
    int lv[8];
    int s = 0;
    #pragma unroll
    for (int u = 0; u < 8; ++u) {
        int id = i0 + u;
        lv[u] = (id < nN) ? deg[id] : 0;
        s += lv[u];
    }
    sd[t] = s;
    __syncthreads();
    for (int d = 1; d < 256; d <<= 1) {
        int tmp = (t >= d) ? sd[t - d] : 0;
        __syncthreads();
        sd[t] += tmp;
        __syncthreads();
    }
    int run = bsum[b] + sd[t] - s;
    #pragma unroll
    for (int u = 0; u < 8; ++u) {
        int id = i0 + u;
        if (id < nN) start[id] = run;
        run += lv[u];
    }
    if (b == 0 && t == 0) start[nN] = nE;
}

// scatter: indices ONLY; no atomics (rank captured in deg).
__global__ __launch_bounds__(256) void scatter_kernel(
    const int* __restrict__ ei, const int* __restrict__ start,
    const int* __restrict__ rank, int2* __restrict__ spair, int nE)
{
    int e = blockIdx.x * 256 + threadIdx.x;
    if (e >= nE) return;
    int dst = ei[nE + e];
    int pos = start[dst] + rank[e];
    spair[pos] = make_int2(ei[e], e);
}

// ---------------- agg (fused with pre_final): 8 threads/node (head x half) --------
// attr gathered DIRECTLY from f32 ea (128B aligned rows — no over-fetch);
// spair batched via coalesced int2 preload + shfl broadcast.
// Latency-equilibrium floor ~150us (r29 byte-cut was a confirmed null).
__global__ __launch_bounds__(256) void agg_kernel(
    const int* __restrict__ start, const int2* __restrict__ spair,
    const float* __restrict__ ea,
    const unsigned short* __restrict__ q, const unsigned short* __restrict__ k,
    const unsigned short* __restrict__ v, const unsigned short* __restrict__ qp,
    const float* __restrict__ WeT,
    const float* __restrict__ x, const float* __restrict__ skip,
    const float* __restrict__ ln2w, const float* __restrict__ ln2b,
    float* __restrict__ xnf, unsigned short* __restrict__ hbf, int nN)
{
    int t = blockIdx.x * 256 + threadIdx.x;
    int n = t >> 3, sub = t & 7, h = sub >> 1, half = sub & 1;
    if (n >= nN) return;
    int l = threadIdx.x & 63;
    int gbase = l & ~7;

    float qv[8];
    { uint4 r = *(const uint4*)(q + (size_t)n * 64 + h * 16 + half * 8); unp8(r, qv); }
    float pj[16];
    {
        const uint4* r = (const uint4*)(qp + (size_t)n * 128 + h * 32 + half * 16);
        unp8(r[0], pj); unp8(r[1], pj + 8);
    }
    float acc[8], s[16];
    #pragma unroll
    for (int c = 0; c < 8; ++c) acc[c] = 0.f;
    #pragma unroll
    for (int j = 0; j < 16; ++j) s[j] = 0.f;
    float dn = 0.f;

    int i0 = start[n], i1 = start[n + 1];
    #pragma unroll 1
    for (int base = i0; base < i1; base += 8) {
        int myi = base + sub;
        int2 se = (myi < i1) ? spair[myi] : make_int2(0, 0);
        int lim = min(8, i1 - base);
        #pragma unroll 2
        for (int j = 0; j < lim; ++j) {
            int src = __shfl(se.x, gbase + j);
            int e   = __shfl(se.y, gbase + j);
            float attr[16];
            {
                const float4* ar = (const float4*)(ea + (size_t)e * 32 + half * 16);
                #pragma unroll
                for (int ii = 0; ii < 4; ++ii) {
                    float4 u = ar[ii];
                    attr[ii * 4 + 0] = u.x; attr[ii * 4 + 1] = u.y;
                    attr[ii * 4 + 2] = u.z; attr[ii * 4 + 3] = u.w;
                }
            }
            float part = 0.f;
            {
                uint4 r = *(const uint4*)(k + (size_t)src * 64 + h * 16 + half * 8);
                float kt[8];
                unp8(r, kt);
                #pragma unroll
                for (int d = 0; d < 8; ++d) part += qv[d] * kt[d];
            }
            #pragma unroll
            for (int j2 = 0; j2 < 16; ++j2) part += attr[j2] * pj[j2];
            float al = part + __shfl_xor(part, 1);
            float ex = __expf(al * 0.25f);
            dn += ex;
            {
                uint4 r = *(const uint4*)(v + (size_t)src * 64 + h * 16 + half * 8);
                float vt[8];
                unp8(r, vt);
                #pragma unroll
                for (int c = 0; c < 8; ++c) acc[c] += ex * vt[c];
            }
            #pragma unroll
            for (int j2 = 0; j2 < 16; ++j2) s[j2] += ex * attr[j2];
        }
    }

    // factored edge projection, split across the lane pair:
    int ch_own = h * 16 + half * 8;
    int ch_oth = h * 16 + (1 - half) * 8;
    float proj_oth[8];
    float po[8];
    #pragma unroll
    for (int c = 0; c < 8; ++c) {
        const float* wo = WeT + (size_t)(ch_own + c) * 32 + half * 16;
        const float* wx = WeT + (size_t)(ch_oth + c) * 32 + half * 16;
        float a = 0.f, b = 0.f;
        #pragma unroll
        for (int j = 0; j < 16; ++j) { a += wo[j] * s[j]; b += wx[j] * s[j]; }
        po[c] = a; proj_oth[c] = b;
    }
    #pragma unroll
    for (int c = 0; c < 8; ++c) acc[c] += po[c] + __shfl_xor(proj_oth[c], 1);

    // ---- fused pre_final epilogue ----
    float inv = dn != 0.f ? 1.f / dn : 0.f;
    float xn[8];
    {
        const float4* xr = (const float4*)(x + (size_t)n * 64 + ch_own);
        const float4* sr = (const float4*)(skip + (size_t)n * 64 + ch_own);
        float4 x0 = xr[0], x1 = xr[1], s0 = sr[0], s1 = sr[1];
        xn[0] = x0.x + s0.x + acc[0] * inv;
        xn[1] = x0.y + s0.y + acc[1] * inv;
        xn[2] = x0.z + s0.z + acc[2] * inv;
        xn[3] = x0.w + s0.w + acc[3] * inv;
        xn[4] = x1.x + s1.x + acc[4] * inv;
        xn[5] = x1.y + s1.y + acc[5] * inv;
        xn[6] = x1.z + s1.z + acc[6] * inv;
        xn[7] = x1.w + s1.w + acc[7] * inv;
    }
    float sm = 0.f, sq = 0.f;
    #pragma unroll
    for (int c = 0; c < 8; ++c) { sm += xn[c]; sq += xn[c] * xn[c]; }
    sm += __shfl_xor(sm, 1); sm += __shfl_xor(sm, 2); sm += __shfl_xor(sm, 4);
    sq += __shfl_xor(sq, 1); sq += __shfl_xor(sq, 2); sq += __shfl_xor(sq, 4);
    float m = sm * (1.f / 64.f);
    float var = sq * (1.f / 64.f) - m * m;
    float rstd = rsqrtf(var + 1e-5f);

    float4* xw = (float4*)(xnf + (size_t)n * 64 + ch_own);
    xw[0] = make_float4(xn[0], xn[1], xn[2], xn[3]);
    xw[1] = make_float4(xn[4], xn[5], xn[6], xn[7]);

    const float4* wr = (const float4*)(ln2w + ch_own);
    const float4* br = (const float4*)(ln2b + ch_own);
    float4 w0 = wr[0], w1 = wr[1], b0 = br[0], b1 = br[1];
    float h0 = (xn[0] - m) * rstd * w0.x + b0.x;
    float h1 = (xn[1] - m) * rstd * w0.y + b0.y;
    float h2 = (xn[2] - m) * rstd * w0.z + b0.z;
    float h3 = (xn[3] - m) * rstd * w0.w + b0.w;
    float h4 = (xn[4] - m) * rstd * w1.x + b1.x;
    float h5 = (xn[5] - m) * rstd * w1.y + b1.y;
    float h6 = (xn[6] - m) * rstd * w1.z + b1.z;
    float h7 = (xn[7] - m) * rstd * w1.w + b1.w;
    uint2* hw = (uint2*)(hbf + (size_t)n * 64 + ch_own);
    hw[0] = make_uint2(pack2(h0, h1), pack2(h2, h3));
    hw[1] = make_uint2(pack2(h4, h5), pack2(h6, h7));
}

// ---------------- mlp: h @ W1 -> GELU -> @ W2 + xn + b2, all MFMA ----------------
__global__ __launch_bounds__(256, 2) void mlp_kernel(
    const unsigned short* __restrict__ hbf, const float* __restrict__ xnf,
    const unsigned short* __restrict__ W1frag, const unsigned short* __restrict__ W2frag,
    const float* __restrict__ b1, const float* __restrict__ b2,
    float* __restrict__ out, int nN)
{
    __shared__ unsigned short lw1[8192];
    __shared__ unsigned short lw2[8192];
    __shared__ unsigned short lh[4096];
    __shared__ unsigned short lg[8192];
    int tid = threadIdx.x;
    int m0 = blockIdx.x * 64;

    {
        const uint4* g1 = (const uint4*)W1frag;
        uint4* l1 = (uint4*)lw1;
        #pragma unroll
        for (int i = 0; i < 4; ++i) l1[tid + i * 256] = g1[tid + i * 256];
        const uint4* g2 = (const uint4*)W2frag;
        uint4* l2 = (uint4*)lw2;
        #pragma unroll
        for (int i = 0; i < 4; ++i) l2[tid + i * 256] = g2[tid + i * 256];
    }
    {
        int r = tid >> 2, p = tid & 3;
        int n = m0 + r;
        uint4 a = make_uint4(0, 0, 0, 0), b = a;
        if (n < nN) {
            const uint4* hr = (const uint4*)(hbf + (size_t)n * 64);
            a = hr[p]; b = hr[p + 4];
        }
        uint4* lhv = (uint4*)lh;
        lhv[r * 8 + (p ^ (r & 7))] = a;
        lhv[r * 8 + ((p + 4) ^ (r & 7))] = b;
    }
    __syncthreads();

    int w = tid >> 6, l = tid & 63;
    int hi = l >> 4, colb = l & 15;
    int lr = w * 16 + colb;
    s16x8 a0 = *(const s16x8*)&lh[(lr * 8 + ((0 + hi) ^ (lr & 7))) * 8];
    s16x8 a1 = *(const s16x8*)&lh[(lr * 8 + ((4 + hi) ^ (lr & 7))) * 8];

    f32x4 acc1[8];
    #pragma unroll
    for (int nt = 0; nt < 8; ++nt) {
        float bb = b1[nt * 16 + colb];
        acc1[nt] = (f32x4){bb, bb, bb, bb};
    }
    #pragma unroll
    for (int nt = 0; nt < 8; ++nt) {
        s16x8 b0 = *(const s16x8*)&lw1[((nt * 2 + 0) * 64 + l) * 8];
        s16x8 b1v = *(const s16x8*)&lw1[((nt * 2 + 1) * 64 + l) * 8];
        acc1[nt] = __builtin_amdgcn_mfma_f32_16x16x32_bf16(a0, b0, acc1[nt], 0, 0, 0);
        acc1[nt] = __builtin_amdgcn_mfma_f32_16x16x32_bf16(a1, b1v, acc1[nt], 0, 0, 0);
    }

    int rb = w * 16 + hi * 4;
    #pragma unroll
    for (int nt = 0; nt < 8; ++nt) {
        int c = nt * 16 + colb;
        int chunk = c >> 3;
        #pragma unroll
        for (int r = 0; r < 4; ++r) {
            float a = acc1[nt][r];
            float gl = 0.5f * a * (1.f + erff(a * 0.70710678118f));
            int node = rb + r;
            lg[node * 128 + (chunk ^ (node & 15)) * 8 + (c & 7)] = f2bf(gl);
        }
    }
    __syncthreads();

    s16x8 ag[4];
    #pragma unroll
    for (int kh = 0; kh < 4; ++kh) {
        int chunk = kh * 4 + hi;
        ag[kh] = *(const s16x8*)&lg[lr * 128 + ((chunk ^ (lr & 15)) * 8)];
    }
    f32x4 acc2[4];
    #pragma unroll
    for (int nt = 0; nt < 4; ++nt) acc2[nt] = (f32x4){0.f, 0.f, 0.f, 0.f};
    #pragma unroll
    for (int nt = 0; nt < 4; ++nt) {
        #pragma unroll
        for (int kh = 0; kh < 4; ++kh) {
            s16x8 bb = *(const s16x8*)&lw2[((nt * 4 + kh) * 64 + l) * 8];
            acc2[nt] = __builtin_amdgcn_mfma_f32_16x16x32_bf16(ag[kh], bb, acc2[nt], 0, 0, 0);
        }
    }

    #pragma unroll
    for (int nt = 0; nt < 4; ++nt) {
        int c = nt * 16 + colb;
        float b2v = b2[c];
        #pragma unroll
        for (int r = 0; r < 4; ++r) {
            int node = m0 + rb + r;
            if (node >= nN) continue;
            out[(size_t)node * 64 + c] = acc2[nt][r] + xnf[(size_t)node * 64 + c] + b2v;
        }
    }
}

extern "C" void kernel_launch(void* const* d_in, const int* in_sizes, int n_in,
                              void* d_out, int out_size, void* d_ws, size_t ws_size,
                              hipStream_t stream)
{
    const float* x    = (const float*)d_in[0];
    const int*   ei   = (const int*)d_in[1];
    const float* ea   = (const float*)d_in[2];
    const float* ln1w = (const float*)d_in[3];
    const float* ln1b = (const float*)d_in[4];
    const float* ln2w = (const float*)d_in[5];
    const float* ln2b = (const float*)d_in[6];
    const float* Wq   = (const float*)d_in[7];
    const float* bq   = (const float*)d_in[8];
    const float* Wk   = (const float*)d_in[9];
    const float* bk   = (const float*)d_in[10];
    const float* Wv   = (const float*)d_in[11];
    const float* bv   = (const float*)d_in[12];
    const float* We   = (const float*)d_in[13];
    const float* Wsk  = (const float*)d_in[14];
    const float* bsk  = (const float*)d_in[15];
    const float* W1   = (const float*)d_in[16];
    const float* b1   = (const float*)d_in[17];
    const float* W2   = (const float*)d_in[18];
    const float* b2   = (const float*)d_in[19];

    int nN = in_sizes[0] / 64;
    int nE = in_sizes[1] / 2;
    int nb = (nN + 2047) / 2048;

    char* wsb = (char*)d_ws;
    size_t off = 0;
    auto take = [&](size_t bytes) {
        char* p = wsb + off;
        off += (bytes + 255) & ~(size_t)255;
        return p;
    };
    unsigned short* q  = (unsigned short*)take((size_t)nN * 64 * 2);
    unsigned short* kk = (unsigned short*)take((size_t)nN * 64 * 2);
    unsigned short* vv = (unsigned short*)take((size_t)nN * 64 * 2);
    unsigned short* qp = (unsigned short*)take((size_t)nN * 128 * 2);
    float* skip    = (float*)take((size_t)nN * 64 * 4);
    float* WallT   = (float*)take(384 * 64 * 4);
    float* biasAll = (float*)take(384 * 4);
    float* WeT     = (float*)take(64 * 32 * 4);
    float* W1T     = (float*)take(128 * 64 * 4);
    unsigned short* Wfrag  = (unsigned short*)take(24576 * 2);
    unsigned short* W1frag = (unsigned short*)take(8192 * 2);
    unsigned short* W2frag = (unsigned short*)take(8192 * 2);
    float* xnf = (float*)take((size_t)nN * 64 * 4);
    unsigned short* hbf = (unsigned short*)take((size_t)nN * 64 * 2);
    int* deg    = (int*)take((size_t)nN * 4);
    int* startp = (int*)take((size_t)(nN + 1) * 4);
    int* bsum   = (int*)take((size_t)(nb + 1) * 4);
    int* rank   = (int*)take((size_t)nE * 4);
    int2* spair = (int2*)take((size_t)nE * 8);

    (void)hipMemsetAsync(deg, 0, (size_t)nN * 4, stream);
    prep_kernel<<<138, 256, 0, stream>>>(Wq, bq, Wk, bk, Wv, bv, We, Wsk, bsk, W1,
                                         WallT, biasAll, WeT, W1T);
    prep2_kernel<<<96, 256, 0, stream>>>(WallT, Wfrag);
    prep3_kernel<<<64, 256, 0, stream>>>(W1, W2, W1frag, W2frag);
    gemm_kernel<<<(nN + 63) / 64, 256, 0, stream>>>(x, ln1w, ln1b, Wfrag, biasAll,
                                                    q, kk, vv, qp, skip, nN);
    deg_kernel<<<(nE + 255) / 256, 256, 0, stream>>>(ei, deg, rank, nE);
    scanA_kernel<<<nb, 256, 0, stream>>>(deg, bsum, nN);
    scanB_kernel<<<1, 1024, 0, stream>>>(bsum, nb);
    scanC_kernel<<<nb, 256, 0, stream>>>(deg, bsum, startp, nN, nE);
    scatter_kernel<<<(nE + 255) / 256, 256, 0, stream>>>(ei, startp, rank, spair, nE);
    agg_kernel<<<((size_t)nN * 8 + 255) / 256, 256, 0, stream>>>(
        startp, spair, ea, q, kk, vv, qp, WeT, x, skip, ln2w, ln2b,
        xnf, hbf, nN);
    mlp_kernel<<<(nN + 63) / 64, 256, 0, stream>>>(hbf, xnf, W1frag, W2frag,
                                                   b1, b2, (float*)d_out, nN);
}